// Round 12
// baseline (160.560 us; speedup 1.0000x reference)
//
#include <hip/hip_runtime.h>

#define L_SEQ 1024
typedef unsigned short ush;
typedef __attribute__((ext_vector_type(8))) short short8;
typedef __attribute__((ext_vector_type(4))) float f32x4;

#define MFMA __builtin_amdgcn_mfma_f32_16x16x32_bf16

// q planes carry 0.125 * log2(e) so attention probs are exp2(s) directly.
// NOTE (R11 lesson): exp MUST be exp2f (OCML-precise). Raw v_exp_f32's biased
// error does not cancel in softmax ratios -> absmax 2.4e-4 -> 4.6e-3 FAIL.
#define Q_PRESCALE 0.18033688011112042f

__device__ __forceinline__ ush f2bf(float x) {
  union { float f; unsigned u; } c; c.f = x;
  unsigned r = c.u + 0x7FFF + ((c.u >> 16) & 1);
  return (ush)(r >> 16);
}
__device__ __forceinline__ float bf2f(ush h) {
  union { unsigned u; float f; } c; c.u = ((unsigned)h) << 16;
  return c.f;
}
__device__ __forceinline__ void gload16(const void* g, void* l) {
  __builtin_amdgcn_global_load_lds(
      (const __attribute__((address_space(1))) unsigned*)g,
      (__attribute__((address_space(3))) unsigned*)l, 16, 0, 0);
}

// ---------------------------------------------------------------------------
// Split fp32 tensor -> bf16 hi plane + bf16 lo plane (lo = x - hi).
// ---------------------------------------------------------------------------
struct SplitA {
  const float* s0; const float* s1; const float* s2; const float* s3;
  const float* s4; const float* s5; const float* s6;
  ush* d0; ush* d1; ush* d2; ush* d3; ush* d4; ush* d5; ush* d6;
};
__global__ __launch_bounds__(256) void split_all(SplitA a) {
  const int ti = blockIdx.y;
  const float* s; ush* d; int n;
  switch (ti) {
    case 0: s = a.s0; d = a.d0; n = 1 << 21; break;
    case 1: s = a.s1; d = a.d1; n = 1 << 21; break;
    case 2: s = a.s2; d = a.d2; n = 1 << 21; break;
    case 3: s = a.s3; d = a.d3; n = 1 << 20; break;
    case 4: s = a.s4; d = a.d4; n = 1 << 20; break;
    case 5: s = a.s5; d = a.d5; n = 1 << 20; break;
    default: s = a.s6; d = a.d6; n = 1 << 20; break;
  }
  int i = (blockIdx.x * 256 + threadIdx.x) * 8;
  if (i >= n) return;
  float4 x0 = *(const float4*)(s + i);
  float4 x1 = *(const float4*)(s + i + 4);
  float xs[8] = {x0.x, x0.y, x0.z, x0.w, x1.x, x1.y, x1.z, x1.w};
  ush h[8], l[8];
  #pragma unroll
  for (int j = 0; j < 8; j++) {
    h[j] = f2bf(xs[j]);
    l[j] = f2bf(xs[j] - bf2f(h[j]));
  }
  ushort4 h0 = {h[0], h[1], h[2], h[3]}, h1 = {h[4], h[5], h[6], h[7]};
  ushort4 l0 = {l[0], l[1], l[2], l[3]}, l1 = {l[4], l[5], l[6], l[7]};
  *(ushort4*)(d + i) = h0;     *(ushort4*)(d + i + 4) = h1;
  *(ushort4*)(d + n + i) = l0; *(ushort4*)(d + n + i + 4) = l1;
}

// ---------------------------------------------------------------------------
// Split-bf16 MFMA GEMM. Tile 128x64, BK=64, 4 waves.
// DBUF=1: double-buffered LDS + prefetch-before-compute (for 1-block/CU grids).
// ---------------------------------------------------------------------------
template <int DBUF>
__global__ __launch_bounds__(256) void gemm_sp(
    const ush* __restrict__ Abase, long AzStride, long Aplane,
    const ush* __restrict__ Bbase, long BzStride,
    const float* __restrict__ b0, const float* __restrict__ b1,
    const float* __restrict__ b2,
    float* __restrict__ Yf, ush* __restrict__ Pbase) {
  __shared__ __align__(16) ush lds[DBUF ? 49152 : 24576];
  const int t = threadIdx.x;
  const int z = blockIdx.z;
  const ush* A = Abase + (size_t)z * AzStride;
  const ush* B = Bbase + (size_t)z * BzStride;
  const float* bias = (z == 0) ? b0 : (z == 1) ? b1 : b2;
  const long Bplane = 1024 * 1024;
  const int r0 = blockIdx.x * 128;
  const int n0 = blockIdx.y * 64;
  const int wid = t >> 6, lane = t & 63;
  const int wr = wid >> 1, wc = wid & 1;
  const int sr = t >> 3, ss = t & 7;
  const int sd = ss ^ (sr & 7);
  const int fr = lane & 15, fk = lane >> 4;

  f32x4 acc[4][2];
  #pragma unroll
  for (int mf = 0; mf < 4; mf++)
    #pragma unroll
    for (int nf = 0; nf < 2; nf++)
      acc[mf][nf] = (f32x4){0.f, 0.f, 0.f, 0.f};

  const ush* Ag = A + (size_t)(r0 + sr) * 1024 + sd * 8;
  const ush* Bg = B + (size_t)(n0 + sr) * 1024 + sd * 8;

  auto stage = [&](ush* Lb, int k0) {
    #pragma unroll
    for (int p = 0; p < 2; p++)
      #pragma unroll
      for (int c = 0; c < 4; c++)
        gload16(Ag + (size_t)p * Aplane + (size_t)c * 32 * 1024 + k0,
                Lb + p * 8192 + (c * 256 + t) * 8);
    #pragma unroll
    for (int p = 0; p < 2; p++)
      #pragma unroll
      for (int c = 0; c < 2; c++)
        gload16(Bg + (size_t)p * Bplane + (size_t)c * 32 * 1024 + k0,
                Lb + 16384 + p * 4096 + (c * 256 + t) * 8);
  };
  auto compute = [&](const ush* Lb) {
    #pragma unroll
    for (int g = 0; g < 2; g++) {
      short8 ah[4], al[4], bh[2], bl[2];
      const int sl = ((g * 4 + fk) ^ (fr & 7)) * 8;
      #pragma unroll
      for (int mf = 0; mf < 4; mf++) {
        int row = wr * 64 + mf * 16 + fr;
        ah[mf] = *(const short8*)(Lb + row * 64 + sl);
        al[mf] = *(const short8*)(Lb + 8192 + row * 64 + sl);
      }
      #pragma unroll
      for (int nf = 0; nf < 2; nf++) {
        int row = wc * 32 + nf * 16 + fr;
        bh[nf] = *(const short8*)(Lb + 16384 + row * 64 + sl);
        bl[nf] = *(const short8*)(Lb + 20480 + row * 64 + sl);
      }
      #pragma unroll
      for (int mf = 0; mf < 4; mf++)
        #pragma unroll
        for (int nf = 0; nf < 2; nf++) {
          acc[mf][nf] = MFMA(ah[mf], bh[nf], acc[mf][nf], 0, 0, 0);
          acc[mf][nf] = MFMA(ah[mf], bl[nf], acc[mf][nf], 0, 0, 0);
          acc[mf][nf] = MFMA(al[mf], bh[nf], acc[mf][nf], 0, 0, 0);
        }
    }
  };

  if constexpr (DBUF) {
    stage(lds, 0);
    __syncthreads();
    for (int k0 = 0; k0 < 1024; k0 += 64) {
      const int cur = (k0 >> 6) & 1;
      if (k0 + 64 < 1024) stage(lds + (cur ^ 1) * 24576, k0 + 64);
      compute(lds + cur * 24576);
      __syncthreads();
    }
  } else {
    for (int k0 = 0; k0 < 1024; k0 += 64) {
      __syncthreads();
      stage(lds, k0);
      __syncthreads();
      compute(lds);
    }
  }

  const float oscale = (z == 0) ? Q_PRESCALE : 1.0f;
  ush* Ph = Pbase ? (Pbase + (size_t)z * 4194304) : (ush*)0;
  ush* Pl = Ph ? Ph + 2097152 : (ush*)0;
  #pragma unroll
  for (int nf = 0; nf < 2; nf++) {
    const int col = n0 + wc * 32 + nf * 16 + fr;
    const float bb = bias[col];
    #pragma unroll
    for (int mf = 0; mf < 4; mf++) {
      const int rowb = r0 + wr * 64 + mf * 16 + fk * 4;
      if (Yf) {
        #pragma unroll
        for (int r = 0; r < 4; r++)
          Yf[(size_t)(rowb + r) * 1024 + col] = acc[mf][nf][r] + bb;
      } else if (z != 2) {
        #pragma unroll
        for (int r = 0; r < 4; r++) {
          float v = (acc[mf][nf][r] + bb) * oscale;
          ush hv = f2bf(v);
          Ph[(size_t)(rowb + r) * 1024 + col] = hv;
          Pl[(size_t)(rowb + r) * 1024 + col] = f2bf(v - bf2f(hv));
        }
      } else {
        // z==2 (V): transposed hi-plane only
        ushort4 hv;
        #pragma unroll
        for (int r = 0; r < 4; r++)
          ((ush*)&hv)[r] = f2bf(acc[mf][nf][r] + bb);
        *(ushort4*)&Ph[(size_t)col * 2048 + rowb] = hv;
      }
    }
  }
}

// ---------------------------------------------------------------------------
// Precompute bf16 cross-products: kc4g[b][d][m][4] = cross(k[m+1], k[m]), 0-pad.
// ---------------------------------------------------------------------------
__global__ __launch_bounds__(256) void trip_kc(
    const ush* __restrict__ kh, const ush* __restrict__ kl,
    ush* __restrict__ kc4g) {
  const int t = threadIdx.x;
  const int m = blockIdx.x * 256 + t;
  const int d = blockIdx.y, b = blockIdx.z;
  const int col = 832 + 3 * d;
  size_t r0 = (size_t)(b * 1024 + m) * 1024 + col;
  size_t r1 = (size_t)(b * 1024 + ((m + 1) & 1023)) * 1024 + col;
  float c0 = bf2f(kh[r0]) + bf2f(kl[r0]);
  float c1 = bf2f(kh[r0 + 1]) + bf2f(kl[r0 + 1]);
  float c2 = bf2f(kh[r0 + 2]) + bf2f(kl[r0 + 2]);
  float a0 = bf2f(kh[r1]) + bf2f(kl[r1]);
  float a1 = bf2f(kh[r1 + 1]) + bf2f(kl[r1 + 1]);
  float a2 = bf2f(kh[r1 + 2]) + bf2f(kl[r1 + 2]);
  ushort4 o;
  o.x = f2bf(a1 * c2 - a2 * c1);
  o.y = f2bf(a2 * c0 - a0 * c2);
  o.z = f2bf(a0 * c1 - a1 * c0);
  o.w = 0;
  *(ushort4*)(kc4g + ((size_t)(b * 64 + d) * 1024 + m) * 4) = o;
}

// ---------------------------------------------------------------------------
// Fused attention: blocks [0,416) = normal heads, [416, 2464) = triplet.
// Norm: __syncthreads 2-phase dbuf; Q direct to registers; swapped QK^T;
// ones-MFMA denominator. Trip: verified 16x16x32 body, FULL m-loop unroll
// (LDS addrs become base + imm offset). exp = exp2f (precise; see R11 note).
// ---------------------------------------------------------------------------
struct NormLds {
  ush Kh[2][4096];
  ush Kl[2][4096];
  ush Vt[2][4096];
  unsigned Pb[4][16][20];
};
struct TripLds {
  ush KC[4096];
  ush VT[4 * 1040];
  ush PB[4][16][36];
};
union FusedLds { NormLds n; TripLds t; };

__global__ __launch_bounds__(256) void attn_fused(
    const ush* __restrict__ qh, const ush* __restrict__ ql,
    const ush* __restrict__ kh, const ush* __restrict__ kl,
    const ush* __restrict__ vth, const ush* __restrict__ kc4g,
    ush* __restrict__ ctxh, ush* __restrict__ ctxl) {
  __shared__ __align__(16) FusedLds L;
  const int t = threadIdx.x;
  const int bid = blockIdx.x;
  const int lane = t & 63, w = t >> 6;
  const int c = lane & 15, g = lane >> 4;

  if (bid < 416) {
    // ------------------ normal-head flash attention ------------------
    const int l0 = (bid & 15) * 64;
    const int rem = bid >> 4;
    const int h = rem % 13, b = rem / 13;
    const int hoff = h * 64;
    const int srow = t >> 3, sg = t & 7;

    // Q B-fragments direct from global (q-row = w*16+c, k = kk*32 + g*8 + j)
    short8 ah[2], al[2];
    {
      size_t qbase = (size_t)(b * 1024 + l0 + w * 16 + c) * 1024 + hoff + g * 8;
      ah[0] = *(const short8*)(qh + qbase);
      ah[1] = *(const short8*)(qh + qbase + 32);
      al[0] = *(const short8*)(ql + qbase);
      al[1] = *(const short8*)(ql + qbase + 32);
    }
    auto stageKV = [&](int buf, int m0) {
      #pragma unroll
      for (int cc = 0; cc < 2; cc++) {
        int row = cc * 32 + srow;
        int slot = sg ^ (row & 7);
        size_t srck = (size_t)(b * 1024 + m0 + row) * 1024 + hoff + slot * 8;
        gload16(kh + srck, &L.n.Kh[buf][row * 64 + sg * 8]);
        gload16(kl + srck, &L.n.Kl[buf][row * 64 + sg * 8]);
        size_t srcv = (size_t)(hoff + row) * 2048 + b * 1024 + m0 + slot * 8;
        gload16(vth + srcv, &L.n.Vt[buf][row * 64 + sg * 8]);
      }
    };
    stageKV(0, 0);
    __syncthreads();

    const short8 ones = {0x3F80, 0x3F80, 0x3F80, 0x3F80,
                         0x3F80, 0x3F80, 0x3F80, 0x3F80};
    f32x4 acc[4];
    f32x4 accD = {0.f, 0.f, 0.f, 0.f};
    #pragma unroll
    for (int df = 0; df < 4; df++) acc[df] = (f32x4){0.f, 0.f, 0.f, 0.f};

    for (int step = 0; step < 16; step++) {
      const int cur = step & 1;
      if (step < 15) stageKV(cur ^ 1, (step + 1) * 64);
      const ush* KhC = &L.n.Kh[cur][0];
      const ush* KlC = &L.n.Kl[cur][0];
      const ush* VtC = &L.n.Vt[cur][0];
      // --- S^T = K·Q^T : lane holds s[q=w*16+c][k = nf*16 + g*4 + r] ---
      f32x4 s[4];
      #pragma unroll
      for (int nf = 0; nf < 4; nf++) {
        s[nf] = (f32x4){0.f, 0.f, 0.f, 0.f};
        #pragma unroll
        for (int kk = 0; kk < 2; kk++) {
          int kr = nf * 16 + c;
          int slot = (kk * 4 + g) ^ (kr & 7);
          short8 bh = *(const short8*)(KhC + kr * 64 + slot * 8);
          short8 bl = *(const short8*)(KlC + kr * 64 + slot * 8);
          s[nf] = MFMA(bh, ah[kk], s[nf], 0, 0, 0);
          s[nf] = MFMA(bh, al[kk], s[nf], 0, 0, 0);
          s[nf] = MFMA(bl, ah[kk], s[nf], 0, 0, 0);
        }
      }
      // --- p = 2^s via exp2f (bounded; no max subtraction) ---
      float pr[4][4];
      #pragma unroll
      for (int nf = 0; nf < 4; nf++)
        #pragma unroll
        for (int r = 0; r < 4; r++) pr[nf][r] = exp2f(s[nf][r]);
      // --- PV + denominator, per 32-k half-window ---
      #pragma unroll
      for (int kk = 0; kk < 2; kk++) {
        #pragma unroll
        for (int nn = 0; nn < 2; nn++) {
          const int nf = kk * 2 + nn;
          unsigned u0, u1;
          asm("v_cvt_pk_bf16_f32 %0, %1, %2" : "=v"(u0) : "v"(pr[nf][0]), "v"(pr[nf][1]));
          asm("v_cvt_pk_bf16_f32 %0, %1, %2" : "=v"(u1) : "v"(pr[nf][2]), "v"(pr[nf][3]));
          *(uint2*)&L.n.Pb[w][c][nn * 8 + g * 2] = (uint2){u0, u1};
        }
        short8 pa = *(const short8*)&L.n.Pb[w][c][g * 4];
        accD = MFMA(pa, ones, accD, 0, 0, 0);
        #pragma unroll
        for (int df = 0; df < 4; df++) {
          int dr = df * 16 + c;
          int slot = (kk * 4 + g) ^ (dr & 7);
          short8 bv = *(const short8*)(VtC + dr * 64 + slot * 8);
          acc[df] = MFMA(pa, bv, acc[df], 0, 0, 0);
        }
      }
      __syncthreads();
    }
    float inv[4];
    #pragma unroll
    for (int r = 0; r < 4; r++) inv[r] = 1.0f / accD[r];
    #pragma unroll
    for (int df = 0; df < 4; df++)
      #pragma unroll
      for (int r = 0; r < 4; r++) {
        float o = acc[df][r] * inv[r];
        size_t off = (size_t)(b * 1024 + l0 + w * 16 + g * 4 + r) * 1024 + hoff + df * 16 + c;
        ush hv = f2bf(o);
        ctxh[off] = hv;
        ctxl[off] = f2bf(o - bf2f(hv));
      }
  } else {
    // ------------------ triplet attention ------------------
    const int t2 = bid - 416;
    const int l0 = (t2 & 15) * 64;
    const int d = (t2 >> 4) & 63, b = t2 >> 10;
    const int col = 832 + 3 * d;

    const ush* kcsrc = kc4g + (size_t)(b * 64 + d) * 4096;
    gload16(kcsrc + t * 8, L.t.KC + t * 8);
    gload16(kcsrc + 2048 + t * 8, L.t.KC + 2048 + t * 8);

    {
      int row = t >> 6, chunk = t & 63;
      ush* dst = L.t.VT + row * 1040 + chunk * 16;
      if (row < 3) {
        const ush* src = vth + (size_t)(col + row) * 2048 + b * 1024 + chunk * 16;
        uint4 v0 = *(const uint4*)(src);
        uint4 v1 = *(const uint4*)(src + 8);
        *(uint4*)(dst) = v0;
        *(uint4*)(dst + 8) = v1;
      } else {
        uint4 onesv = {0x3F803F80u, 0x3F803F80u, 0x3F803F80u, 0x3F803F80u};
        *(uint4*)(dst) = onesv;
        *(uint4*)(dst + 8) = onesv;
      }
    }

    short8 qB = {0, 0, 0, 0, 0, 0, 0, 0};
    {
      size_t qr = (size_t)(b * 1024 + l0 + w * 16 + c) * 1024 + col;
      float q0 = bf2f(qh[qr]) + bf2f(ql[qr]);
      float q1 = bf2f(qh[qr + 1]) + bf2f(ql[qr + 1]);
      float q2 = bf2f(qh[qr + 2]) + bf2f(ql[qr + 2]);
      if (g == 0) {
        qB[0] = (short)f2bf(q0);
        qB[1] = (short)f2bf(q1);
        qB[2] = (short)f2bf(q2);
      }
    }
    __syncthreads();

    f32x4 acc = {0.f, 0.f, 0.f, 0.f};
    ush* pb = &L.t.PB[w][0][0];
    // FULL unroll: all LDS addresses become loop-invariant base + imm offset.
    #pragma unroll
    for (int m0 = 0; m0 < 1024; m0 += 32) {
      short8 a0 = {0, 0, 0, 0, 0, 0, 0, 0}, a1 = {0, 0, 0, 0, 0, 0, 0, 0};
      *(uint2*)&a0 = *(const uint2*)(L.t.KC + (m0 + c) * 4);
      *(uint2*)&a1 = *(const uint2*)(L.t.KC + (m0 + 16 + c) * 4);
      f32x4 z = {0.f, 0.f, 0.f, 0.f};
      f32x4 s0 = MFMA(a0, qB, z, 0, 0, 0);
      f32x4 s1 = MFMA(a1, qB, z, 0, 0, 0);
      float p0 = exp2f(fabsf(s0[0])), p1 = exp2f(fabsf(s0[1]));
      float p2 = exp2f(fabsf(s0[2])), p3 = exp2f(fabsf(s0[3]));
      float p4 = exp2f(fabsf(s1[0])), p5 = exp2f(fabsf(s1[1]));
      float p6 = exp2f(fabsf(s1[2])), p7 = exp2f(fabsf(s1[3]));
      unsigned k01, k23, k45, k67;
      asm("v_cvt_pk_bf16_f32 %0, %1, %2" : "=v"(k01) : "v"(p0), "v"(p1));
      asm("v_cvt_pk_bf16_f32 %0, %1, %2" : "=v"(k23) : "v"(p2), "v"(p3));
      asm("v_cvt_pk_bf16_f32 %0, %1, %2" : "=v"(k45) : "v"(p4), "v"(p5));
      asm("v_cvt_pk_bf16_f32 %0, %1, %2" : "=v"(k67) : "v"(p6), "v"(p7));
      *(uint2*)(pb + c * 36 + 4 * g) = (uint2){k01, k23};
      *(uint2*)(pb + c * 36 + 16 + 4 * g) = (uint2){k45, k67};
      short8 pf;
      *(uint2*)&pf = *(const uint2*)(pb + c * 36 + 8 * g);
      *((uint2*)&pf + 1) = *(const uint2*)(pb + c * 36 + 8 * g + 4);
      short8 vf = *(const short8*)(L.t.VT + (c & 3) * 1040 + m0 + 8 * g);
      acc = MFMA(vf, pf, acc, 0, 0, 0);
    }
    if (g == 0) {
      const float inv = 1.0f / acc[3];
      size_t off = (size_t)(b * 1024 + l0 + w * 16 + c) * 1024 + col;
      #pragma unroll
      for (int comp = 0; comp < 3; comp++) {
        float o = acc[comp] * inv;
        ush hv = f2bf(o);
        ctxh[off + comp] = hv;
        ctxl[off + comp] = f2bf(o - bf2f(hv));
      }
    }
  }
}

// ---------------------------------------------------------------------------
extern "C" void kernel_launch(void* const* d_in, const int* in_sizes, int n_in,
                              void* d_out, int out_size, void* d_ws, size_t ws_size,
                              hipStream_t stream) {
  const float* query = (const float*)d_in[0];
  const float* key   = (const float*)d_in[1];
  const float* value = (const float*)d_in[2];
  const float* Wq = (const float*)d_in[4];
  const float* bq = (const float*)d_in[5];
  const float* Wk = (const float*)d_in[6];
  const float* bk = (const float*)d_in[7];
  const float* Wv = (const float*)d_in[8];
  const float* bv = (const float*)d_in[9];
  const float* Wo = (const float*)d_in[10];
  const float* bo = (const float*)d_in[11];
  float* out = (float*)d_out;

  char* W = (char*)d_ws;
  const size_t MB = 1 << 20;
  ush* qs  = (ush*)(W + 0 * MB);
  ush* ks  = (ush*)(W + 8 * MB);
  ush* vs  = (ush*)(W + 16 * MB);
  ush* Wqs = (ush*)(W + 24 * MB);
  ush* Wks = (ush*)(W + 28 * MB);
  ush* Wvs = (ush*)(W + 32 * MB);
  ush* Wos = (ush*)(W + 36 * MB);
  ush* planes = (ush*)(W + 40 * MB);
  ush* qh  = planes;
  ush* ql  = planes + 2097152;
  ush* khp = planes + 4194304;
  ush* klp = planes + 6291456;
  ush* vth = planes + 8388608;
  ush* ctxh = qs;                       // alias input splits (dead after QKV GEMM)
  ush* ctxl = qs + 2097152;
  ush* kc4g = ks;                       // alias k input split (dead after QKV GEMM)

  SplitA sa = {query, key, value, Wq, Wk, Wv, Wo,
               qs, ks, vs, Wqs, Wks, Wvs, Wos};
  split_all<<<dim3(1024, 7), 256, 0, stream>>>(sa);

  gemm_sp<0><<<dim3(16, 16, 3), 256, 0, stream>>>(
      qs, (long)(4 * 1024 * 1024), (long)(2 * 1024 * 1024),
      Wqs, (long)(2 * 1024 * 1024),
      bq, bk, bv,
      (float*)0, planes);

  trip_kc<<<dim3(4, 64, 2), 256, 0, stream>>>(khp, klp, kc4g);

  attn_fused<<<dim3(416 + 2048), 256, 0, stream>>>(
      qh, ql, khp, klp, vth, kc4g, ctxh, ctxl);

  gemm_sp<1><<<dim3(16, 16, 1), 256, 0, stream>>>(
      ctxh, 0L, (long)(2 * 1024 * 1024),
      Wos, 0L,
      bo, bo, bo,
      out, (ush*)0);
}

// Round 13
// 146.967 us; speedup vs baseline: 1.0925x; 1.0925x over previous
//
#include <hip/hip_runtime.h>

#define L_SEQ 1024
typedef unsigned short ush;
typedef __attribute__((ext_vector_type(8))) short short8;
typedef __attribute__((ext_vector_type(4))) float f32x4;

#define MFMA __builtin_amdgcn_mfma_f32_16x16x32_bf16

// q planes carry 0.125 * log2(e) so attention probs are exp2(s) directly.
// NOTE (R11 lesson): exp MUST be exp2f (OCML-precise). Raw v_exp_f32's biased
// error does not cancel in softmax ratios -> absmax 2.4e-4 -> 4.6e-3 FAIL.
#define Q_PRESCALE 0.18033688011112042f

__device__ __forceinline__ ush f2bf(float x) {
  union { float f; unsigned u; } c; c.f = x;
  unsigned r = c.u + 0x7FFF + ((c.u >> 16) & 1);
  return (ush)(r >> 16);
}
__device__ __forceinline__ float bf2f(ush h) {
  union { unsigned u; float f; } c; c.u = ((unsigned)h) << 16;
  return c.f;
}
__device__ __forceinline__ void gload16(const void* g, void* l) {
  __builtin_amdgcn_global_load_lds(
      (const __attribute__((address_space(1))) unsigned*)g,
      (__attribute__((address_space(3))) unsigned*)l, 16, 0, 0);
}

// ---------------------------------------------------------------------------
// Split fp32 tensor -> bf16 hi plane + bf16 lo plane (lo = x - hi).
// ---------------------------------------------------------------------------
struct SplitA {
  const float* s0; const float* s1; const float* s2; const float* s3;
  const float* s4; const float* s5; const float* s6;
  ush* d0; ush* d1; ush* d2; ush* d3; ush* d4; ush* d5; ush* d6;
};
__global__ __launch_bounds__(256) void split_all(SplitA a) {
  const int ti = blockIdx.y;
  const float* s; ush* d; int n;
  switch (ti) {
    case 0: s = a.s0; d = a.d0; n = 1 << 21; break;
    case 1: s = a.s1; d = a.d1; n = 1 << 21; break;
    case 2: s = a.s2; d = a.d2; n = 1 << 21; break;
    case 3: s = a.s3; d = a.d3; n = 1 << 20; break;
    case 4: s = a.s4; d = a.d4; n = 1 << 20; break;
    case 5: s = a.s5; d = a.d5; n = 1 << 20; break;
    default: s = a.s6; d = a.d6; n = 1 << 20; break;
  }
  int i = (blockIdx.x * 256 + threadIdx.x) * 8;
  if (i >= n) return;
  float4 x0 = *(const float4*)(s + i);
  float4 x1 = *(const float4*)(s + i + 4);
  float xs[8] = {x0.x, x0.y, x0.z, x0.w, x1.x, x1.y, x1.z, x1.w};
  ush h[8], l[8];
  #pragma unroll
  for (int j = 0; j < 8; j++) {
    h[j] = f2bf(xs[j]);
    l[j] = f2bf(xs[j] - bf2f(h[j]));
  }
  ushort4 h0 = {h[0], h[1], h[2], h[3]}, h1 = {h[4], h[5], h[6], h[7]};
  ushort4 l0 = {l[0], l[1], l[2], l[3]}, l1 = {l[4], l[5], l[6], l[7]};
  *(ushort4*)(d + i) = h0;     *(ushort4*)(d + i + 4) = h1;
  *(ushort4*)(d + n + i) = l0; *(ushort4*)(d + n + i + 4) = l1;
}

// ---------------------------------------------------------------------------
// Split-bf16 MFMA GEMM. Tile 128x64, BK=64, 4 waves.
// DBUF=1: double-buffered LDS + prefetch-before-compute (for 1-block/CU grids).
// ---------------------------------------------------------------------------
template <int DBUF>
__global__ __launch_bounds__(256) void gemm_sp(
    const ush* __restrict__ Abase, long AzStride, long Aplane,
    const ush* __restrict__ Bbase, long BzStride,
    const float* __restrict__ b0, const float* __restrict__ b1,
    const float* __restrict__ b2,
    float* __restrict__ Yf, ush* __restrict__ Pbase) {
  __shared__ __align__(16) ush lds[DBUF ? 49152 : 24576];
  const int t = threadIdx.x;
  const int z = blockIdx.z;
  const ush* A = Abase + (size_t)z * AzStride;
  const ush* B = Bbase + (size_t)z * BzStride;
  const float* bias = (z == 0) ? b0 : (z == 1) ? b1 : b2;
  const long Bplane = 1024 * 1024;
  const int r0 = blockIdx.x * 128;
  const int n0 = blockIdx.y * 64;
  const int wid = t >> 6, lane = t & 63;
  const int wr = wid >> 1, wc = wid & 1;
  const int sr = t >> 3, ss = t & 7;
  const int sd = ss ^ (sr & 7);
  const int fr = lane & 15, fk = lane >> 4;

  f32x4 acc[4][2];
  #pragma unroll
  for (int mf = 0; mf < 4; mf++)
    #pragma unroll
    for (int nf = 0; nf < 2; nf++)
      acc[mf][nf] = (f32x4){0.f, 0.f, 0.f, 0.f};

  const ush* Ag = A + (size_t)(r0 + sr) * 1024 + sd * 8;
  const ush* Bg = B + (size_t)(n0 + sr) * 1024 + sd * 8;

  auto stage = [&](ush* Lb, int k0) {
    #pragma unroll
    for (int p = 0; p < 2; p++)
      #pragma unroll
      for (int c = 0; c < 4; c++)
        gload16(Ag + (size_t)p * Aplane + (size_t)c * 32 * 1024 + k0,
                Lb + p * 8192 + (c * 256 + t) * 8);
    #pragma unroll
    for (int p = 0; p < 2; p++)
      #pragma unroll
      for (int c = 0; c < 2; c++)
        gload16(Bg + (size_t)p * Bplane + (size_t)c * 32 * 1024 + k0,
                Lb + 16384 + p * 4096 + (c * 256 + t) * 8);
  };
  auto compute = [&](const ush* Lb) {
    #pragma unroll
    for (int g = 0; g < 2; g++) {
      short8 ah[4], al[4], bh[2], bl[2];
      const int sl = ((g * 4 + fk) ^ (fr & 7)) * 8;
      #pragma unroll
      for (int mf = 0; mf < 4; mf++) {
        int row = wr * 64 + mf * 16 + fr;
        ah[mf] = *(const short8*)(Lb + row * 64 + sl);
        al[mf] = *(const short8*)(Lb + 8192 + row * 64 + sl);
      }
      #pragma unroll
      for (int nf = 0; nf < 2; nf++) {
        int row = wc * 32 + nf * 16 + fr;
        bh[nf] = *(const short8*)(Lb + 16384 + row * 64 + sl);
        bl[nf] = *(const short8*)(Lb + 20480 + row * 64 + sl);
      }
      #pragma unroll
      for (int mf = 0; mf < 4; mf++)
        #pragma unroll
        for (int nf = 0; nf < 2; nf++) {
          acc[mf][nf] = MFMA(ah[mf], bh[nf], acc[mf][nf], 0, 0, 0);
          acc[mf][nf] = MFMA(ah[mf], bl[nf], acc[mf][nf], 0, 0, 0);
          acc[mf][nf] = MFMA(al[mf], bh[nf], acc[mf][nf], 0, 0, 0);
        }
    }
  };

  if constexpr (DBUF) {
    stage(lds, 0);
    __syncthreads();
    for (int k0 = 0; k0 < 1024; k0 += 64) {
      const int cur = (k0 >> 6) & 1;
      if (k0 + 64 < 1024) stage(lds + (cur ^ 1) * 24576, k0 + 64);
      compute(lds + cur * 24576);
      __syncthreads();
    }
  } else {
    for (int k0 = 0; k0 < 1024; k0 += 64) {
      __syncthreads();
      stage(lds, k0);
      __syncthreads();
      compute(lds);
    }
  }

  const float oscale = (z == 0) ? Q_PRESCALE : 1.0f;
  ush* Ph = Pbase ? (Pbase + (size_t)z * 4194304) : (ush*)0;
  ush* Pl = Ph ? Ph + 2097152 : (ush*)0;
  #pragma unroll
  for (int nf = 0; nf < 2; nf++) {
    const int col = n0 + wc * 32 + nf * 16 + fr;
    const float bb = bias[col];
    #pragma unroll
    for (int mf = 0; mf < 4; mf++) {
      const int rowb = r0 + wr * 64 + mf * 16 + fk * 4;
      if (Yf) {
        #pragma unroll
        for (int r = 0; r < 4; r++)
          Yf[(size_t)(rowb + r) * 1024 + col] = acc[mf][nf][r] + bb;
      } else if (z != 2) {
        #pragma unroll
        for (int r = 0; r < 4; r++) {
          float v = (acc[mf][nf][r] + bb) * oscale;
          ush hv = f2bf(v);
          Ph[(size_t)(rowb + r) * 1024 + col] = hv;
          Pl[(size_t)(rowb + r) * 1024 + col] = f2bf(v - bf2f(hv));
        }
      } else {
        // z==2 (V): transposed hi-plane only
        ushort4 hv;
        #pragma unroll
        for (int r = 0; r < 4; r++)
          ((ush*)&hv)[r] = f2bf(acc[mf][nf][r] + bb);
        *(ushort4*)&Ph[(size_t)col * 2048 + rowb] = hv;
      }
    }
  }
}

// ---------------------------------------------------------------------------
// Precompute bf16 cross-products: kc4g[b][d][m][4] = cross(k[m+1], k[m]), 0-pad.
// ---------------------------------------------------------------------------
__global__ __launch_bounds__(256) void trip_kc(
    const ush* __restrict__ kh, const ush* __restrict__ kl,
    ush* __restrict__ kc4g) {
  const int t = threadIdx.x;
  const int m = blockIdx.x * 256 + t;
  const int d = blockIdx.y, b = blockIdx.z;
  const int col = 832 + 3 * d;
  size_t r0 = (size_t)(b * 1024 + m) * 1024 + col;
  size_t r1 = (size_t)(b * 1024 + ((m + 1) & 1023)) * 1024 + col;
  float c0 = bf2f(kh[r0]) + bf2f(kl[r0]);
  float c1 = bf2f(kh[r0 + 1]) + bf2f(kl[r0 + 1]);
  float c2 = bf2f(kh[r0 + 2]) + bf2f(kl[r0 + 2]);
  float a0 = bf2f(kh[r1]) + bf2f(kl[r1]);
  float a1 = bf2f(kh[r1 + 1]) + bf2f(kl[r1 + 1]);
  float a2 = bf2f(kh[r1 + 2]) + bf2f(kl[r1 + 2]);
  ushort4 o;
  o.x = f2bf(a1 * c2 - a2 * c1);
  o.y = f2bf(a2 * c0 - a0 * c2);
  o.z = f2bf(a0 * c1 - a1 * c0);
  o.w = 0;
  *(ushort4*)(kc4g + ((size_t)(b * 64 + d) * 1024 + m) * 4) = o;
}

// ---------------------------------------------------------------------------
// Fused attention: blocks [0,416) = normal heads, [416, 2464) = triplet.
// Occupancy-first restructure (R12 counters: 19% occ, latency-bound):
//  - Norm: SINGLE-buffer K/V (24KB), stage/sync/compute/sync per step.
//  - Trip: even/odd P sub-buffers break cross-iteration LDS serialization.
// Union LDS 54.3KB -> 29.7KB => 5 blocks/CU.
// ---------------------------------------------------------------------------
struct NormLds {
  ush Kh[4096];
  ush Kl[4096];
  ush Vt[4096];
  unsigned Pb[4][16][20];
};
struct TripLds {
  ush KC[4096];
  ush VT[4 * 1040];
  ush PB[4][2][16][36];   // [wave][iter parity][l][m-local]
};
union FusedLds { NormLds n; TripLds t; };

__global__ __launch_bounds__(256) void attn_fused(
    const ush* __restrict__ qh, const ush* __restrict__ ql,
    const ush* __restrict__ kh, const ush* __restrict__ kl,
    const ush* __restrict__ vth, const ush* __restrict__ kc4g,
    ush* __restrict__ ctxh, ush* __restrict__ ctxl) {
  __shared__ __align__(16) FusedLds L;
  const int t = threadIdx.x;
  const int bid = blockIdx.x;
  const int lane = t & 63, w = t >> 6;
  const int c = lane & 15, g = lane >> 4;

  if (bid < 416) {
    // ------------------ normal-head flash attention ------------------
    const int l0 = (bid & 15) * 64;
    const int rem = bid >> 4;
    const int h = rem % 13, b = rem / 13;
    const int hoff = h * 64;
    const int srow = t >> 3, sg = t & 7;

    // Q B-fragments direct from global (q-row = w*16+c, k = kk*32 + g*8 + j)
    short8 ah[2], al[2];
    {
      size_t qbase = (size_t)(b * 1024 + l0 + w * 16 + c) * 1024 + hoff + g * 8;
      ah[0] = *(const short8*)(qh + qbase);
      ah[1] = *(const short8*)(qh + qbase + 32);
      al[0] = *(const short8*)(ql + qbase);
      al[1] = *(const short8*)(ql + qbase + 32);
    }
    auto stageKV = [&](int m0) {
      #pragma unroll
      for (int cc = 0; cc < 2; cc++) {
        int row = cc * 32 + srow;
        int slot = sg ^ (row & 7);
        size_t srck = (size_t)(b * 1024 + m0 + row) * 1024 + hoff + slot * 8;
        gload16(kh + srck, &L.n.Kh[row * 64 + sg * 8]);
        gload16(kl + srck, &L.n.Kl[row * 64 + sg * 8]);
        size_t srcv = (size_t)(hoff + row) * 2048 + b * 1024 + m0 + slot * 8;
        gload16(vth + srcv, &L.n.Vt[row * 64 + sg * 8]);
      }
    };

    const short8 ones = {0x3F80, 0x3F80, 0x3F80, 0x3F80,
                         0x3F80, 0x3F80, 0x3F80, 0x3F80};
    f32x4 acc[4];
    f32x4 accD = {0.f, 0.f, 0.f, 0.f};
    #pragma unroll
    for (int df = 0; df < 4; df++) acc[df] = (f32x4){0.f, 0.f, 0.f, 0.f};

    for (int step = 0; step < 16; step++) {
      if (step > 0) __syncthreads();   // prior compute done before overwrite
      stageKV(step * 64);
      __syncthreads();                 // staged tile visible
      // --- S^T = K·Q^T : lane holds s[q=w*16+c][k = nf*16 + g*4 + r] ---
      f32x4 s[4];
      #pragma unroll
      for (int nf = 0; nf < 4; nf++) {
        s[nf] = (f32x4){0.f, 0.f, 0.f, 0.f};
        #pragma unroll
        for (int kk = 0; kk < 2; kk++) {
          int kr = nf * 16 + c;
          int slot = (kk * 4 + g) ^ (kr & 7);
          short8 bh = *(const short8*)(&L.n.Kh[kr * 64 + slot * 8]);
          short8 bl = *(const short8*)(&L.n.Kl[kr * 64 + slot * 8]);
          s[nf] = MFMA(bh, ah[kk], s[nf], 0, 0, 0);
          s[nf] = MFMA(bh, al[kk], s[nf], 0, 0, 0);
          s[nf] = MFMA(bl, ah[kk], s[nf], 0, 0, 0);
        }
      }
      // --- p = 2^s via exp2f (bounded; no max subtraction) ---
      float pr[4][4];
      #pragma unroll
      for (int nf = 0; nf < 4; nf++)
        #pragma unroll
        for (int r = 0; r < 4; r++) pr[nf][r] = exp2f(s[nf][r]);
      // --- PV + denominator, per 32-k half-window ---
      #pragma unroll
      for (int kk = 0; kk < 2; kk++) {
        #pragma unroll
        for (int nn = 0; nn < 2; nn++) {
          const int nf = kk * 2 + nn;
          unsigned u0, u1;
          asm("v_cvt_pk_bf16_f32 %0, %1, %2" : "=v"(u0) : "v"(pr[nf][0]), "v"(pr[nf][1]));
          asm("v_cvt_pk_bf16_f32 %0, %1, %2" : "=v"(u1) : "v"(pr[nf][2]), "v"(pr[nf][3]));
          *(uint2*)&L.n.Pb[w][c][nn * 8 + g * 2] = (uint2){u0, u1};
        }
        short8 pa = *(const short8*)&L.n.Pb[w][c][g * 4];
        accD = MFMA(pa, ones, accD, 0, 0, 0);
        #pragma unroll
        for (int df = 0; df < 4; df++) {
          int dr = df * 16 + c;
          int slot = (kk * 4 + g) ^ (dr & 7);
          short8 bv = *(const short8*)(&L.n.Vt[dr * 64 + slot * 8]);
          acc[df] = MFMA(pa, bv, acc[df], 0, 0, 0);
        }
      }
    }
    float inv[4];
    #pragma unroll
    for (int r = 0; r < 4; r++) inv[r] = 1.0f / accD[r];
    #pragma unroll
    for (int df = 0; df < 4; df++)
      #pragma unroll
      for (int r = 0; r < 4; r++) {
        float o = acc[df][r] * inv[r];
        size_t off = (size_t)(b * 1024 + l0 + w * 16 + g * 4 + r) * 1024 + hoff + df * 16 + c;
        ush hv = f2bf(o);
        ctxh[off] = hv;
        ctxl[off] = f2bf(o - bf2f(hv));
      }
  } else {
    // ------------------ triplet attention ------------------
    const int t2 = bid - 416;
    const int l0 = (t2 & 15) * 64;
    const int d = (t2 >> 4) & 63, b = t2 >> 10;
    const int col = 832 + 3 * d;

    const ush* kcsrc = kc4g + (size_t)(b * 64 + d) * 4096;
    gload16(kcsrc + t * 8, L.t.KC + t * 8);
    gload16(kcsrc + 2048 + t * 8, L.t.KC + 2048 + t * 8);

    {
      int row = t >> 6, chunk = t & 63;
      ush* dst = L.t.VT + row * 1040 + chunk * 16;
      if (row < 3) {
        const ush* src = vth + (size_t)(col + row) * 2048 + b * 1024 + chunk * 16;
        uint4 v0 = *(const uint4*)(src);
        uint4 v1 = *(const uint4*)(src + 8);
        *(uint4*)(dst) = v0;
        *(uint4*)(dst + 8) = v1;
      } else {
        uint4 onesv = {0x3F803F80u, 0x3F803F80u, 0x3F803F80u, 0x3F803F80u};
        *(uint4*)(dst) = onesv;
        *(uint4*)(dst + 8) = onesv;
      }
    }

    short8 qB = {0, 0, 0, 0, 0, 0, 0, 0};
    {
      size_t qr = (size_t)(b * 1024 + l0 + w * 16 + c) * 1024 + col;
      float q0 = bf2f(qh[qr]) + bf2f(ql[qr]);
      float q1 = bf2f(qh[qr + 1]) + bf2f(ql[qr + 1]);
      float q2 = bf2f(qh[qr + 2]) + bf2f(ql[qr + 2]);
      if (g == 0) {
        qB[0] = (short)f2bf(q0);
        qB[1] = (short)f2bf(q1);
        qB[2] = (short)f2bf(q2);
      }
    }
    __syncthreads();

    f32x4 acc = {0.f, 0.f, 0.f, 0.f};
    #pragma unroll 2
    for (int m0 = 0; m0 < 1024; m0 += 32) {
      ush* pb = &L.t.PB[w][(m0 >> 5) & 1][0][0];   // even/odd P buffer
      short8 a0 = {0, 0, 0, 0, 0, 0, 0, 0}, a1 = {0, 0, 0, 0, 0, 0, 0, 0};
      *(uint2*)&a0 = *(const uint2*)(L.t.KC + (m0 + c) * 4);
      *(uint2*)&a1 = *(const uint2*)(L.t.KC + (m0 + 16 + c) * 4);
      f32x4 z = {0.f, 0.f, 0.f, 0.f};
      f32x4 s0 = MFMA(a0, qB, z, 0, 0, 0);
      f32x4 s1 = MFMA(a1, qB, z, 0, 0, 0);
      float p0 = exp2f(fabsf(s0[0])), p1 = exp2f(fabsf(s0[1]));
      float p2 = exp2f(fabsf(s0[2])), p3 = exp2f(fabsf(s0[3]));
      float p4 = exp2f(fabsf(s1[0])), p5 = exp2f(fabsf(s1[1]));
      float p6 = exp2f(fabsf(s1[2])), p7 = exp2f(fabsf(s1[3]));
      unsigned k01, k23, k45, k67;
      asm("v_cvt_pk_bf16_f32 %0, %1, %2" : "=v"(k01) : "v"(p0), "v"(p1));
      asm("v_cvt_pk_bf16_f32 %0, %1, %2" : "=v"(k23) : "v"(p2), "v"(p3));
      asm("v_cvt_pk_bf16_f32 %0, %1, %2" : "=v"(k45) : "v"(p4), "v"(p5));
      asm("v_cvt_pk_bf16_f32 %0, %1, %2" : "=v"(k67) : "v"(p6), "v"(p7));
      *(uint2*)(pb + c * 36 + 4 * g) = (uint2){k01, k23};
      *(uint2*)(pb + c * 36 + 16 + 4 * g) = (uint2){k45, k67};
      short8 pf;
      *(uint2*)&pf = *(const uint2*)(pb + c * 36 + 8 * g);
      *((uint2*)&pf + 1) = *(const uint2*)(pb + c * 36 + 8 * g + 4);
      short8 vf = *(const short8*)(L.t.VT + (c & 3) * 1040 + m0 + 8 * g);
      acc = MFMA(vf, pf, acc, 0, 0, 0);
    }
    if (g == 0) {
      const float inv = 1.0f / acc[3];
      size_t off = (size_t)(b * 1024 + l0 + w * 16 + c) * 1024 + col;
      #pragma unroll
      for (int comp = 0; comp < 3; comp++) {
        float o = acc[comp] * inv;
        ush hv = f2bf(o);
        ctxh[off + comp] = hv;
        ctxl[off + comp] = f2bf(o - bf2f(hv));
      }
    }
  }
}

// ---------------------------------------------------------------------------
extern "C" void kernel_launch(void* const* d_in, const int* in_sizes, int n_in,
                              void* d_out, int out_size, void* d_ws, size_t ws_size,
                              hipStream_t stream) {
  const float* query = (const float*)d_in[0];
  const float* key   = (const float*)d_in[1];
  const float* value = (const float*)d_in[2];
  const float* Wq = (const float*)d_in[4];
  const float* bq = (const float*)d_in[5];
  const float* Wk = (const float*)d_in[6];
  const float* bk = (const float*)d_in[7];
  const float* Wv = (const float*)d_in[8];
  const float* bv = (const float*)d_in[9];
  const float* Wo = (const float*)d_in[10];
  const float* bo = (const float*)d_in[11];
  float* out = (float*)d_out;

  char* W = (char*)d_ws;
  const size_t MB = 1 << 20;
  ush* qs  = (ush*)(W + 0 * MB);
  ush* ks  = (ush*)(W + 8 * MB);
  ush* vs  = (ush*)(W + 16 * MB);
  ush* Wqs = (ush*)(W + 24 * MB);
  ush* Wks = (ush*)(W + 28 * MB);
  ush* Wvs = (ush*)(W + 32 * MB);
  ush* Wos = (ush*)(W + 36 * MB);
  ush* planes = (ush*)(W + 40 * MB);
  ush* qh  = planes;
  ush* ql  = planes + 2097152;
  ush* khp = planes + 4194304;
  ush* klp = planes + 6291456;
  ush* vth = planes + 8388608;
  ush* ctxh = qs;                       // alias input splits (dead after QKV GEMM)
  ush* ctxl = qs + 2097152;
  ush* kc4g = ks;                       // alias k input split (dead after QKV GEMM)

  SplitA sa = {query, key, value, Wq, Wk, Wv, Wo,
               qs, ks, vs, Wqs, Wks, Wvs, Wos};
  split_all<<<dim3(1024, 7), 256, 0, stream>>>(sa);

  gemm_sp<0><<<dim3(16, 16, 3), 256, 0, stream>>>(
      qs, (long)(4 * 1024 * 1024), (long)(2 * 1024 * 1024),
      Wqs, (long)(2 * 1024 * 1024),
      bq, bk, bv,
      (float*)0, planes);

  trip_kc<<<dim3(4, 64, 2), 256, 0, stream>>>(khp, klp, kc4g);

  attn_fused<<<dim3(416 + 2048), 256, 0, stream>>>(
      qh, ql, khp, klp, vth, kc4g, ctxh, ctxl);

  gemm_sp<1><<<dim3(16, 16, 1), 256, 0, stream>>>(
      ctxh, 0L, (long)(2 * 1024 * 1024),
      Wos, 0L,
      bo, bo, bo,
      out, (ush*)0);
}